// Round 4
// baseline (1249.589 us; speedup 1.0000x reference)
//
#include <hip/hip_runtime.h>
#include <math.h>

#define Bb   4
#define Ss   16
#define Nn   2048
#define Ff   32
#define Ee   16384
#define EFf  8
#define Hh   64
#define HB2  32
#define E2c  (Ee + Nn)          // 18432
#define RTOT (Bb*Ss*Nn)         // 131072
#define Mm   (Ss*Nn)            // 32768

__device__ __forceinline__ float sigf(float x) { return 1.f / (1.f + __expf(-x)); }
__device__ __forceinline__ float tanhfast(float x) { return 2.f / (1.f + __expf(-2.f * x)) - 1.f; }

// 64-lane all-reduce sum: 4 DPP adds (VALU) + swizzle xor16 + shfl xor32.
__device__ __forceinline__ float rsum64(float v) {
  int x;
  x = __builtin_amdgcn_update_dpp(0, __float_as_int(v), 0xB1, 0xF, 0xF, true);   // quad_perm xor1
  v += __int_as_float(x);
  x = __builtin_amdgcn_update_dpp(0, __float_as_int(v), 0x4E, 0xF, 0xF, true);   // quad_perm xor2
  v += __int_as_float(x);
  x = __builtin_amdgcn_update_dpp(0, __float_as_int(v), 0x124, 0xF, 0xF, true);  // row_ror:4
  v += __int_as_float(x);
  x = __builtin_amdgcn_update_dpp(0, __float_as_int(v), 0x128, 0xF, 0xF, true);  // row_ror:8
  v += __int_as_float(x);
  x = __builtin_amdgcn_ds_swizzle(__float_as_int(v), 0x401F);                    // xor16 (in 32-grp)
  v += __int_as_float(x);
  v += __shfl_xor(v, 32, 64);                                                    // cross-half
  return v;
}

// ---------------------------------------------------------------------------
// Self-loop attr accumulation
// ---------------------------------------------------------------------------
__global__ __launch_bounds__(256) void k_loop_accum(
    const int* __restrict__ ei, const float* __restrict__ ea,
    float* __restrict__ cntF, float* __restrict__ loopA) {
  int idx = blockIdx.x * 256 + threadIdx.x;
  int e = idx >> 3, j = idx & 7;
  int d = ei[Ee + e];
  atomicAdd(&loopA[d * EFf + j], ea[idx]);
  if (j == 0) atomicAdd(&cntF[d], 1.0f);
}

__global__ __launch_bounds__(256) void k_loop_div(
    float* __restrict__ loopA, const float* __restrict__ cntF) {
  int idx = blockIdx.x * 256 + threadIdx.x;
  loopA[idx] /= fmaxf(cntF[idx >> 3], 1.0f);
}

// ---------------------------------------------------------------------------
// Exclusive scan of per-dst counts (+1 self loop) -> offs[0..2048]
// ---------------------------------------------------------------------------
__global__ __launch_bounds__(256) void k_scan(
    const float* __restrict__ cntF, int* __restrict__ offs) {
  __shared__ int partial[256];
  int tid = threadIdx.x;
  int base = tid * 8;
  int vals[8];
  int s = 0;
  for (int i = 0; i < 8; ++i) {
    int c = (int)cntF[base + i] + 1;
    vals[i] = c;
    s += c;
  }
  partial[tid] = s;
  __syncthreads();
  for (int off = 1; off < 256; off <<= 1) {
    int v = partial[tid];
    int add = (tid >= off) ? partial[tid - off] : 0;
    __syncthreads();
    partial[tid] = v + add;
    __syncthreads();
  }
  int run = (tid == 0) ? 0 : partial[tid - 1];
  for (int i = 0; i < 8; ++i) {
    offs[base + i] = run;
    run += vals[i];
  }
  if (tid == 255) offs[Nn] = run;
}

__global__ __launch_bounds__(256) void k_scatter(
    const int* __restrict__ ei, const int* __restrict__ offs,
    int* __restrict__ fillI, int* __restrict__ posOf, int* __restrict__ srcA) {
  int e = blockIdx.x * 256 + threadIdx.x;
  if (e >= E2c) return;
  int d = (e < Ee) ? ei[Ee + e] : (e - Ee);
  int s = (e < Ee) ? ei[e]      : (e - Ee);
  int pos = offs[d] + atomicAdd(&fillI[d], 1);
  posOf[e] = pos;
  srcA[pos] = s;
}

// ---------------------------------------------------------------------------
// Transpose Wih/Whh to k-major: WT[l][k][j<192: ih, 192..383: hh]
// ---------------------------------------------------------------------------
__global__ __launch_bounds__(256) void k_wtr(
    const float* __restrict__ Wih, const float* __restrict__ Whh,
    float* __restrict__ WT) {
  int idx = blockIdx.x * 256 + threadIdx.x;   // 2*64*384 = 49152
  int l = idx / (64 * 384);
  int k = (idx / 384) & 63;
  int j = idx % 384;
  float v = (j < 192) ? Wih[((size_t)l * 192 + j) * 64 + k]
                      : Whh[((size_t)l * 192 + (j - 192)) * 64 + k];
  WT[idx] = v;
}

// ---------------------------------------------------------------------------
// ep = ea_f @ We[l], written in CSR order (EPc[posOf[e]])
// ---------------------------------------------------------------------------
__global__ __launch_bounds__(256) void k_ep(
    const float* __restrict__ ea, const float* __restrict__ loopA,
    const float* __restrict__ We, const int* __restrict__ posOf,
    float* __restrict__ EPc) {
  __shared__ float wlds[EFf * Hh];
  int tid = threadIdx.x;
  if (tid < EFf * Hh) wlds[tid] = We[tid];
  if (tid + 256 < EFf * Hh) wlds[tid + 256] = We[tid + 256];
  __syncthreads();
  int idx = blockIdx.x * 256 + tid;
  int e = idx >> 6, j = idx & 63;
  const float* a = (e < Ee) ? (ea + (size_t)e * EFf) : (loopA + (size_t)(e - Ee) * EFf);
  float acc = 0.f;
#pragma unroll
  for (int k = 0; k < EFf; ++k) acc += a[k] * wlds[k * Hh + j];
  EPc[(((size_t)posOf[e]) << 6) + j] = acc;
}

// ---------------------------------------------------------------------------
// proj: block = 64 rows x 4 col-groups. X staged coalesced into LDS,
// column reads (stride 33 -> 2-way bank, free), W via uniform s_load,
// output routed through LDS for coalesced stores.
// ---------------------------------------------------------------------------
__global__ __launch_bounds__(256) void k_proj(
    const float* __restrict__ X, const float* __restrict__ Wp,
    const float* __restrict__ bp, float* __restrict__ Out) {
  __shared__ float xa[64 * 33];
  __shared__ float ob[64 * 65];
  int tid = threadIdx.x;
  int r64 = tid & 63, j0 = (tid >> 6) << 4;
  int m0 = blockIdx.x << 6;
  for (int i = 0; i < 2; ++i) {
    int lin = (i << 10) + (tid << 2);      // 0..2047
    int r = lin >> 5, c = lin & 31;
    float4 v = *(const float4*)(X + ((size_t)(m0 + r) << 5) + c);
    float* dp = &xa[r * 33 + c];
    dp[0] = v.x; dp[1] = v.y; dp[2] = v.z; dp[3] = v.w;
  }
  __syncthreads();
  float acc[16];
#pragma unroll
  for (int jj = 0; jj < 16; ++jj) acc[jj] = bp[j0 + jj];
  for (int k = 0; k < 32; ++k) {
    float xv = xa[r64 * 33 + k];
    const float* wk = Wp + (k << 6) + j0;
#pragma unroll
    for (int jj = 0; jj < 16; ++jj) acc[jj] = fmaf(xv, wk[jj], acc[jj]);
  }
#pragma unroll
  for (int jj = 0; jj < 16; ++jj) ob[r64 * 65 + j0 + jj] = acc[jj];
  __syncthreads();
  for (int i = 0; i < 16; ++i) {
    int lin = (i << 8) + tid;
    int r = lin >> 6, c = lin & 63;
    Out[((size_t)(m0 + r) << 6) + c] = ob[r * 65 + c];
  }
}

// ---------------------------------------------------------------------------
// Fused XL/XR, block-row structure (same pattern as k_proj, K=64, 2 outputs)
// ---------------------------------------------------------------------------
__global__ __launch_bounds__(256) void k_xlr(
    const float* __restrict__ X,
    const float* __restrict__ Wl_, const float* __restrict__ bl_,
    const float* __restrict__ Wr_, const float* __restrict__ br_,
    float* __restrict__ XL, float* __restrict__ XR) {
  __shared__ float xa[64 * 65];
  __shared__ float ob[64 * 65];
  int tid = threadIdx.x;
  int r64 = tid & 63, j0 = (tid >> 6) << 4;
  int m0 = blockIdx.x << 6;
  for (int i = 0; i < 4; ++i) {
    int lin = (i << 10) + (tid << 2);
    int r = lin >> 6, c = lin & 63;
    float4 v = *(const float4*)(X + ((size_t)(m0 + r) << 6) + c);
    float* dp = &xa[r * 65 + c];
    dp[0] = v.x; dp[1] = v.y; dp[2] = v.z; dp[3] = v.w;
  }
  __syncthreads();
  float accL[16], accR[16];
#pragma unroll
  for (int jj = 0; jj < 16; ++jj) { accL[jj] = bl_[j0 + jj]; accR[jj] = br_[j0 + jj]; }
  for (int k = 0; k < 64; ++k) {
    float xv = xa[r64 * 65 + k];
    const float* wL = Wl_ + (k << 6) + j0;
    const float* wR = Wr_ + (k << 6) + j0;
#pragma unroll
    for (int jj = 0; jj < 16; ++jj) {
      accL[jj] = fmaf(xv, wL[jj], accL[jj]);
      accR[jj] = fmaf(xv, wR[jj], accR[jj]);
    }
  }
  __syncthreads();   // xa reads done -> reuse xa for L output
#pragma unroll
  for (int jj = 0; jj < 16; ++jj) {
    xa[r64 * 65 + j0 + jj] = accL[jj];
    ob[r64 * 65 + j0 + jj] = accR[jj];
  }
  __syncthreads();
  for (int i = 0; i < 16; ++i) {
    int lin = (i << 8) + tid;
    int r = lin >> 6, c = lin & 63;
    XL[((size_t)(m0 + r) << 6) + c] = xa[r * 65 + c];
    XR[((size_t)(m0 + r) << 6) + c] = ob[r * 65 + c];
  }
}

// ---------------------------------------------------------------------------
// GATv2: wave per (g,d), lane = h. DPP reduce, 8-wide masked chunks.
// ---------------------------------------------------------------------------
__global__ __launch_bounds__(256) void k_gat(
    const float* __restrict__ XL, float* __restrict__ XR_HG,
    const float* __restrict__ EPc, const int* __restrict__ offs,
    const int* __restrict__ srcA,
    const float* __restrict__ att, const float* __restrict__ gbl) {
  int gw = (blockIdx.x * 256 + threadIdx.x) >> 6;
  int lane = threadIdx.x & 63;
  int g = gw >> 11;
  int d = gw & (Nn - 1);
  float attv = att[lane];
  float gbv = gbl[lane];
  size_t rowbase = ((size_t)gw) << 6;
  float xr = XR_HG[rowbase + lane];
  int p0 = offs[d], p1 = offs[d + 1];
  int nE = p1 - p0;
  int nE4 = nE < 64 ? nE : 64;
  int soff = 0;
  if (lane < nE4) soff = srcA[p0 + lane] << 8;           // byte offset of src row
  const char* XLg = (const char*)(XL + (((size_t)g * Nn) << 6)) + (lane << 2);
  const char* EPp = (const char*)(EPc + (((size_t)p0) << 6)) + (lane << 2);
  float Ssum = 0.f, acc = 0.f;
  int nCh = (nE4 + 7) >> 3;
  for (int c = 0; c < nCh; ++c) {
    int p = c << 3;
    float xl[8], vv[8];
#pragma unroll
    for (int u = 0; u < 8; ++u) {
      int pu = p + u;
      int pc = pu < nE4 ? pu : nE4 - 1;                  // clamp (masked later)
      int so = __shfl(soff, pc, 64);
      xl[u] = *(const float*)(XLg + so);
      float ep = *(const float*)(EPp + (pc << 8));
      float m = xl[u] + xr + ep;
      m = fmaxf(m, 0.2f * m);                            // leaky_relu(0.2)
      vv[u] = m * attv;
    }
#pragma unroll
    for (int u = 0; u < 8; ++u) vv[u] = rsum64(vv[u]);
#pragma unroll
    for (int u = 0; u < 8; ++u) {
      float v = (p + u < nE4) ? vv[u] : -1e30f;
      float w = __expf(v);
      Ssum += w;
      acc = fmaf(w, xl[u], acc);
    }
  }
  for (int p = 64; p < nE; ++p) {                        // pathological tail
    int s = srcA[p0 + p];
    float xlv = *(const float*)(XLg + (s << 8));
    float ep = *(const float*)(EPp + (p << 8));
    float m = xlv + xr + ep; m = fmaxf(m, 0.2f * m);
    float w = __expf(rsum64(m * attv));
    Ssum += w; acc = fmaf(w, xlv, acc);
  }
  XR_HG[rowbase + lane] = acc / Ssum + gbv;
}

// ---------------------------------------------------------------------------
// Fully fused per-layer GRU: one block owns 64 rows for all 4 t-steps.
// h state lives in LDS; hg_t staged coalesced each step; W via s_load.
// ---------------------------------------------------------------------------
__global__ __launch_bounds__(256) void k_gru_fused(
    const float* __restrict__ hg_all,    // [4][Mm][64]
    const float* __restrict__ WTl,       // [64][384] k-major
    const float* __restrict__ bih, const float* __restrict__ bhh,
    float* __restrict__ hout_all) {      // [4][Mm][64]
  __shared__ float xg[64 * 65];
  __shared__ float hh[64 * 65];
  int tid = threadIdx.x;
  int r64 = tid & 63, j0 = (tid >> 6) << 4;
  int m0 = blockIdx.x << 6;
#pragma unroll 1
  for (int t = 0; t < 4; ++t) {
    __syncthreads();                     // prev-t readers of xg/hh done
    const float* src = hg_all + (((size_t)(t * Mm + m0)) << 6);
    for (int i = 0; i < 4; ++i) {
      int lin = (i << 10) + (tid << 2);
      int r = lin >> 6, c = lin & 63;
      float4 v = *(const float4*)(src + lin);
      float* dp = &xg[r * 65 + c];
      dp[0] = v.x; dp[1] = v.y; dp[2] = v.z; dp[3] = v.w;
    }
    __syncthreads();
    float acc[6][16];
#pragma unroll
    for (int gg = 0; gg < 3; ++gg)
#pragma unroll
      for (int jj = 0; jj < 16; ++jj) {
        acc[gg][jj]     = bih[(gg << 6) + j0 + jj];
        acc[3 + gg][jj] = bhh[(gg << 6) + j0 + jj];
      }
    if (t == 0) {
      for (int k = 0; k < 64; ++k) {
        float xv = xg[r64 * 65 + k];
        const float* wk = WTl + k * 384 + j0;
#pragma unroll
        for (int gg = 0; gg < 3; ++gg)
#pragma unroll
          for (int jj = 0; jj < 16; ++jj)
            acc[gg][jj] = fmaf(xv, wk[(gg << 6) + jj], acc[gg][jj]);
      }
    } else {
      for (int k = 0; k < 64; ++k) {
        float xv = xg[r64 * 65 + k];
        float hv = hh[r64 * 65 + k];
        const float* wk = WTl + k * 384 + j0;
#pragma unroll
        for (int gg = 0; gg < 3; ++gg)
#pragma unroll
          for (int jj = 0; jj < 16; ++jj) {
            acc[gg][jj]     = fmaf(xv, wk[(gg << 6) + jj],       acc[gg][jj]);
            acc[3 + gg][jj] = fmaf(hv, wk[192 + (gg << 6) + jj], acc[3 + gg][jj]);
          }
      }
    }
    float o[16];
#pragma unroll
    for (int jj = 0; jj < 16; ++jj) {
      float hp = (t == 0) ? 0.f : hh[r64 * 65 + j0 + jj];
      float rg = sigf(acc[0][jj] + acc[3][jj]);
      float zg = sigf(acc[1][jj] + acc[4][jj]);
      float ng = tanhfast(acc[2][jj] + rg * acc[5][jj]);
      o[jj] = (1.f - zg) * ng + zg * hp;
    }
    __syncthreads();                     // all hh reads done
#pragma unroll
    for (int jj = 0; jj < 16; ++jj) hh[r64 * 65 + j0 + jj] = o[jj];
    __syncthreads();
    float* dst = hout_all + (((size_t)(t * Mm + m0)) << 6);
    for (int i = 0; i < 4; ++i) {
      int lin = (i << 10) + (tid << 2);
      int r = lin >> 6, c = lin & 63;
      float* sp = &hh[r * 65 + c];
      *(float4*)(dst + lin) = make_float4(sp[0], sp[1], sp[2], sp[3]);
    }
  }
}

// ---------------------------------------------------------------------------
// Output heads
// ---------------------------------------------------------------------------
__global__ __launch_bounds__(256) void k_heads(
    const float* __restrict__ Xb,
    const float* __restrict__ oW1, const float* __restrict__ ob1,
    const float* __restrict__ oW2, const float* __restrict__ ob2,
    const float* __restrict__ dW1, const float* __restrict__ db1,
    const float* __restrict__ dW2, const float* __restrict__ db2,
    float* __restrict__ out) {
  __shared__ float w1o[Hh * HB2], w1d[Hh * HB2];
  __shared__ float w2o[HB2], w2d[HB2], b1o[HB2], b1d[HB2];
  int tid = threadIdx.x;
  for (int idx = tid; idx < Hh * HB2; idx += 256) { w1o[idx] = oW1[idx]; w1d[idx] = dW1[idx]; }
  if (tid < HB2) { w2o[tid] = oW2[tid]; w2d[tid] = dW2[tid]; b1o[tid] = ob1[tid]; b1d[tid] = db1[tid]; }
  __syncthreads();
  int r = blockIdx.x * 256 + tid;
  int b = r >> 11, n = r & (Nn - 1);
  const float* xrow = Xb + (((size_t)b * Ss + (Ss - 1)) * Nn + n) * Hh;
  float x[Hh];
  const float4* xp = (const float4*)xrow;
#pragma unroll
  for (int q = 0; q < Hh / 4; ++q) {
    float4 v = xp[q];
    x[4*q] = v.x; x[4*q+1] = v.y; x[4*q+2] = v.z; x[4*q+3] = v.w;
  }
  float acco = ob2[0], accd = db2[0];
  for (int j = 0; j < HB2; ++j) {
    float ho = b1o[j], hd = b1d[j];
#pragma unroll
    for (int k = 0; k < Hh; ++k) {
      ho += x[k] * w1o[k * HB2 + j];
      hd += x[k] * w1d[k * HB2 + j];
    }
    acco += fmaxf(ho, 0.f) * w2o[j];
    accd += fmaxf(hd, 0.f) * w2d[j];
  }
  out[r] = acco;
  out[Bb * Nn + r] = accd;
}

// ---------------------------------------------------------------------------
extern "C" void kernel_launch(void* const* d_in, const int* in_sizes, int n_in,
                              void* d_out, int out_size, void* d_ws, size_t ws_size,
                              hipStream_t stream) {
  const float* x   = (const float*)d_in[0];
  const int*   ei  = (const int*)d_in[1];
  const float* ea  = (const float*)d_in[2];
  const float* Wp  = (const float*)d_in[3];
  const float* bp  = (const float*)d_in[4];
  const float* Wl  = (const float*)d_in[5];
  const float* bl  = (const float*)d_in[6];
  const float* Wr  = (const float*)d_in[7];
  const float* br  = (const float*)d_in[8];
  const float* We  = (const float*)d_in[9];
  const float* att = (const float*)d_in[10];
  const float* gb  = (const float*)d_in[11];
  const float* Wih = (const float*)d_in[12];
  const float* Whh = (const float*)d_in[13];
  const float* bih = (const float*)d_in[14];
  const float* bhh = (const float*)d_in[15];
  const float* oW1 = (const float*)d_in[16];
  const float* ob1 = (const float*)d_in[17];
  const float* oW2 = (const float*)d_in[18];
  const float* ob2 = (const float*)d_in[19];
  const float* dW1 = (const float*)d_in[20];
  const float* db1 = (const float*)d_in[21];
  const float* dW2 = (const float*)d_in[22];
  const float* db2 = (const float*)d_in[23];
  float* out = (float*)d_out;

  // workspace layout (floats)
  float* f    = (float*)d_ws;
  float* Xb   = f;                          // 131072*64
  float* XLb  = Xb  + (size_t)RTOT * Hh;    // 131072*64
  float* XRb  = XLb + (size_t)RTOT * Hh;    // 131072*64 (hg after k_gat)
  float* EPc  = XRb + (size_t)RTOT * Hh;    // 18432*64 (CSR order)
  float* WTb  = EPc + (size_t)E2c * Hh;     // 2*64*384
  float* cntF = WTb + 2 * 64 * 384;         // 2048
  float* loopA = cntF + Nn;                 // 2048*8
  int*   fillI = (int*)(loopA + Nn * EFf);  // 2048
  int*   offs  = fillI + Nn;                // 2049 (+pad)
  int*   posOf = offs + 2052;               // 18432
  int*   srcA  = posOf + E2c;               // 18432

  hipMemsetAsync(cntF, 0, (size_t)(Nn + Nn * EFf + Nn) * 4, stream);

  k_loop_accum<<<dim3(Ee * EFf / 256), 256, 0, stream>>>(ei, ea, cntF, loopA);
  k_loop_div<<<dim3(Nn * EFf / 256), 256, 0, stream>>>(loopA, cntF);
  k_scan<<<1, 256, 0, stream>>>(cntF, offs);
  k_scatter<<<dim3((E2c + 255) / 256), 256, 0, stream>>>(ei, offs, fillI, posOf, srcA);
  k_wtr<<<dim3(2 * 64 * 384 / 256), 256, 0, stream>>>(Wih, Whh, WTb);

  // X = x @ Wp + bp
  k_proj<<<dim3(RTOT / 64), 256, 0, stream>>>(x, Wp, bp, Xb);

  for (int l = 0; l < 2; ++l) {
    k_ep<<<dim3(E2c * Hh / 256), 256, 0, stream>>>(
        ea, loopA, We + (size_t)l * EFf * Hh, posOf, EPc);
    k_xlr<<<dim3(RTOT / 64), 256, 0, stream>>>(
        Xb, Wl + (size_t)l * Hh * Hh, bl + (size_t)l * Hh,
        Wr + (size_t)l * Hh * Hh, br + (size_t)l * Hh, XLb, XRb);
    k_gat<<<dim3(RTOT * Hh / 256), 256, 0, stream>>>(
        XLb, XRb, EPc, offs, srcA, att + (size_t)l * Hh, gb + (size_t)l * Hh);
    k_gru_fused<<<dim3(Mm / 64), 256, 0, stream>>>(
        XRb, WTb + (size_t)l * 64 * 384, bih + (size_t)l * 192, bhh + (size_t)l * 192, Xb);
  }

  k_heads<<<dim3(Bb * Nn / 256), 256, 0, stream>>>(
      Xb, oW1, ob1, oW2, ob2, dW1, db1, dW2, db2, out);
}

// Round 5
// 693.896 us; speedup vs baseline: 1.8008x; 1.8008x over previous
//
#include <hip/hip_runtime.h>
#include <math.h>

#define Bb   4
#define Ss   16
#define Nn   2048
#define Ff   32
#define Ee   16384
#define EFf  8
#define Hh   64
#define HB2  32
#define E2c  (Ee + Nn)          // 18432
#define RTOT (Bb*Ss*Nn)         // 131072
#define Mm   (Ss*Nn)            // 32768

__device__ __forceinline__ float sigf(float x) { return 1.f / (1.f + __expf(-x)); }
__device__ __forceinline__ float tanhfast(float x) { return 2.f / (1.f + __expf(-2.f * x)) - 1.f; }

// 64-lane all-reduce sum: 4 DPP adds (VALU) + swizzle xor16 + shfl xor32.
__device__ __forceinline__ float rsum64(float v) {
  int x;
  x = __builtin_amdgcn_update_dpp(0, __float_as_int(v), 0xB1, 0xF, 0xF, true);   // quad_perm xor1
  v += __int_as_float(x);
  x = __builtin_amdgcn_update_dpp(0, __float_as_int(v), 0x4E, 0xF, 0xF, true);   // quad_perm xor2
  v += __int_as_float(x);
  x = __builtin_amdgcn_update_dpp(0, __float_as_int(v), 0x124, 0xF, 0xF, true);  // row_ror:4
  v += __int_as_float(x);
  x = __builtin_amdgcn_update_dpp(0, __float_as_int(v), 0x128, 0xF, 0xF, true);  // row_ror:8
  v += __int_as_float(x);
  x = __builtin_amdgcn_ds_swizzle(__float_as_int(v), 0x401F);                    // xor16 (in 32-grp)
  v += __int_as_float(x);
  v += __shfl_xor(v, 32, 64);                                                    // cross-half
  return v;
}

// ---------------------------------------------------------------------------
// Self-loop attr accumulation
// ---------------------------------------------------------------------------
__global__ __launch_bounds__(256) void k_loop_accum(
    const int* __restrict__ ei, const float* __restrict__ ea,
    float* __restrict__ cntF, float* __restrict__ loopA) {
  int idx = blockIdx.x * 256 + threadIdx.x;
  int e = idx >> 3, j = idx & 7;
  int d = ei[Ee + e];
  atomicAdd(&loopA[d * EFf + j], ea[idx]);
  if (j == 0) atomicAdd(&cntF[d], 1.0f);
}

__global__ __launch_bounds__(256) void k_loop_div(
    float* __restrict__ loopA, const float* __restrict__ cntF) {
  int idx = blockIdx.x * 256 + threadIdx.x;
  loopA[idx] /= fmaxf(cntF[idx >> 3], 1.0f);
}

// ---------------------------------------------------------------------------
// Exclusive scan of per-dst counts (+1 self loop) -> offs[0..2048]
// ---------------------------------------------------------------------------
__global__ __launch_bounds__(256) void k_scan(
    const float* __restrict__ cntF, int* __restrict__ offs) {
  __shared__ int partial[256];
  int tid = threadIdx.x;
  int base = tid * 8;
  int vals[8];
  int s = 0;
  for (int i = 0; i < 8; ++i) {
    int c = (int)cntF[base + i] + 1;
    vals[i] = c;
    s += c;
  }
  partial[tid] = s;
  __syncthreads();
  for (int off = 1; off < 256; off <<= 1) {
    int v = partial[tid];
    int add = (tid >= off) ? partial[tid - off] : 0;
    __syncthreads();
    partial[tid] = v + add;
    __syncthreads();
  }
  int run = (tid == 0) ? 0 : partial[tid - 1];
  for (int i = 0; i < 8; ++i) {
    offs[base + i] = run;
    run += vals[i];
  }
  if (tid == 255) offs[Nn] = run;
}

__global__ __launch_bounds__(256) void k_scatter(
    const int* __restrict__ ei, const int* __restrict__ offs,
    int* __restrict__ fillI, int* __restrict__ posOf, int* __restrict__ srcA) {
  int e = blockIdx.x * 256 + threadIdx.x;
  if (e >= E2c) return;
  int d = (e < Ee) ? ei[Ee + e] : (e - Ee);
  int s = (e < Ee) ? ei[e]      : (e - Ee);
  int pos = offs[d] + atomicAdd(&fillI[d], 1);
  posOf[e] = pos;
  srcA[pos] = s;
}

// ---------------------------------------------------------------------------
// Transpose Wih/Whh to k-major: WT[l][k][j<192: ih, 192..383: hh]
// ---------------------------------------------------------------------------
__global__ __launch_bounds__(256) void k_wtr(
    const float* __restrict__ Wih, const float* __restrict__ Whh,
    float* __restrict__ WT) {
  int idx = blockIdx.x * 256 + threadIdx.x;   // 2*64*384 = 49152
  int l = idx / (64 * 384);
  int k = (idx / 384) & 63;
  int j = idx % 384;
  float v = (j < 192) ? Wih[((size_t)l * 192 + j) * 64 + k]
                      : Whh[((size_t)l * 192 + (j - 192)) * 64 + k];
  WT[idx] = v;
}

// ---------------------------------------------------------------------------
// ep = ea_f @ We[l], written in CSR order (EPc[posOf[e]])
// ---------------------------------------------------------------------------
__global__ __launch_bounds__(256) void k_ep(
    const float* __restrict__ ea, const float* __restrict__ loopA,
    const float* __restrict__ We, const int* __restrict__ posOf,
    float* __restrict__ EPc) {
  __shared__ float wlds[EFf * Hh];
  int tid = threadIdx.x;
  if (tid < EFf * Hh) wlds[tid] = We[tid];
  if (tid + 256 < EFf * Hh) wlds[tid + 256] = We[tid + 256];
  __syncthreads();
  int idx = blockIdx.x * 256 + tid;
  int e = idx >> 6, j = idx & 63;
  const float* a = (e < Ee) ? (ea + (size_t)e * EFf) : (loopA + (size_t)(e - Ee) * EFf);
  float acc = 0.f;
#pragma unroll
  for (int k = 0; k < EFf; ++k) acc += a[k] * wlds[k * Hh + j];
  EPc[(((size_t)posOf[e]) << 6) + j] = acc;
}

// ---------------------------------------------------------------------------
// proj: thread = 2 rows x 16-col slice. W slice in LDS (uniform ds_read
// broadcast), A streamed per-lane from global. grid (RTOT/512, 4).
// ---------------------------------------------------------------------------
__global__ __launch_bounds__(256) void k_proj(
    const float* __restrict__ X, const float* __restrict__ Wp,
    const float* __restrict__ bp, float* __restrict__ Out) {
  __shared__ float w[32 * 16];
  int tid = threadIdx.x;
  int j0 = blockIdx.y << 4;
  for (int idx = tid; idx < 32 * 16; idx += 256)
    w[idx] = Wp[((idx >> 4) << 6) + j0 + (idx & 15)];
  __syncthreads();
  int r0 = (blockIdx.x << 9) + tid;   // rows r0 and r0+256
  float acc[2][16];
#pragma unroll
  for (int jj = 0; jj < 16; ++jj) { float b = bp[j0 + jj]; acc[0][jj] = b; acc[1][jj] = b; }
  const float* x0 = X + ((size_t)r0 << 5);
  const float* x1 = x0 + (256 << 5);
  for (int kc = 0; kc < 8; ++kc) {
    float4 a0 = *(const float4*)(x0 + 4 * kc);
    float4 a1 = *(const float4*)(x1 + 4 * kc);
    float a0a[4] = {a0.x, a0.y, a0.z, a0.w};
    float a1a[4] = {a1.x, a1.y, a1.z, a1.w};
#pragma unroll
    for (int q = 0; q < 4; ++q) {
      const float4* wp4 = (const float4*)(w + ((4 * kc + q) << 4));
#pragma unroll
      for (int q4 = 0; q4 < 4; ++q4) {
        float4 wv = wp4[q4];
        acc[0][4*q4+0] = fmaf(a0a[q], wv.x, acc[0][4*q4+0]);
        acc[0][4*q4+1] = fmaf(a0a[q], wv.y, acc[0][4*q4+1]);
        acc[0][4*q4+2] = fmaf(a0a[q], wv.z, acc[0][4*q4+2]);
        acc[0][4*q4+3] = fmaf(a0a[q], wv.w, acc[0][4*q4+3]);
        acc[1][4*q4+0] = fmaf(a1a[q], wv.x, acc[1][4*q4+0]);
        acc[1][4*q4+1] = fmaf(a1a[q], wv.y, acc[1][4*q4+1]);
        acc[1][4*q4+2] = fmaf(a1a[q], wv.z, acc[1][4*q4+2]);
        acc[1][4*q4+3] = fmaf(a1a[q], wv.w, acc[1][4*q4+3]);
      }
    }
  }
#pragma unroll
  for (int rr = 0; rr < 2; ++rr) {
    float* op = Out + (((size_t)(r0 + 256 * rr)) << 6) + j0;
#pragma unroll
    for (int q4 = 0; q4 < 4; ++q4)
      *(float4*)(op + 4 * q4) = make_float4(acc[rr][4*q4], acc[rr][4*q4+1], acc[rr][4*q4+2], acc[rr][4*q4+3]);
  }
}

// ---------------------------------------------------------------------------
// Fused XL/XR: thread = 2 rows x 16-col slice, both W slices in LDS.
// grid (RTOT/512, 4).
// ---------------------------------------------------------------------------
__global__ __launch_bounds__(256) void k_xlr(
    const float* __restrict__ X,
    const float* __restrict__ Wl_, const float* __restrict__ bl_,
    const float* __restrict__ Wr_, const float* __restrict__ br_,
    float* __restrict__ XL, float* __restrict__ XR) {
  __shared__ float wl[64 * 16], wr[64 * 16];
  int tid = threadIdx.x;
  int j0 = blockIdx.y << 4;
  for (int idx = tid; idx < 64 * 16; idx += 256) {
    int k = idx >> 4, jj = idx & 15;
    wl[idx] = Wl_[(k << 6) + j0 + jj];
    wr[idx] = Wr_[(k << 6) + j0 + jj];
  }
  __syncthreads();
  int r0 = (blockIdx.x << 9) + tid;
  float accL[2][16], accR[2][16];
#pragma unroll
  for (int jj = 0; jj < 16; ++jj) {
    float bL = bl_[j0 + jj], bR = br_[j0 + jj];
    accL[0][jj] = bL; accL[1][jj] = bL;
    accR[0][jj] = bR; accR[1][jj] = bR;
  }
  const float* x0 = X + ((size_t)r0 << 6);
  const float* x1 = x0 + (256 << 6);
  for (int kc = 0; kc < 16; ++kc) {
    float4 a0 = *(const float4*)(x0 + 4 * kc);
    float4 a1 = *(const float4*)(x1 + 4 * kc);
    float a0a[4] = {a0.x, a0.y, a0.z, a0.w};
    float a1a[4] = {a1.x, a1.y, a1.z, a1.w};
#pragma unroll
    for (int q = 0; q < 4; ++q) {
      int k = 4 * kc + q;
      const float4* wl4 = (const float4*)(wl + (k << 4));
      const float4* wr4 = (const float4*)(wr + (k << 4));
#pragma unroll
      for (int q4 = 0; q4 < 4; ++q4) {
        float4 wlv = wl4[q4], wrv = wr4[q4];
        accL[0][4*q4+0] = fmaf(a0a[q], wlv.x, accL[0][4*q4+0]);
        accL[0][4*q4+1] = fmaf(a0a[q], wlv.y, accL[0][4*q4+1]);
        accL[0][4*q4+2] = fmaf(a0a[q], wlv.z, accL[0][4*q4+2]);
        accL[0][4*q4+3] = fmaf(a0a[q], wlv.w, accL[0][4*q4+3]);
        accL[1][4*q4+0] = fmaf(a1a[q], wlv.x, accL[1][4*q4+0]);
        accL[1][4*q4+1] = fmaf(a1a[q], wlv.y, accL[1][4*q4+1]);
        accL[1][4*q4+2] = fmaf(a1a[q], wlv.z, accL[1][4*q4+2]);
        accL[1][4*q4+3] = fmaf(a1a[q], wlv.w, accL[1][4*q4+3]);
        accR[0][4*q4+0] = fmaf(a0a[q], wrv.x, accR[0][4*q4+0]);
        accR[0][4*q4+1] = fmaf(a0a[q], wrv.y, accR[0][4*q4+1]);
        accR[0][4*q4+2] = fmaf(a0a[q], wrv.z, accR[0][4*q4+2]);
        accR[0][4*q4+3] = fmaf(a0a[q], wrv.w, accR[0][4*q4+3]);
        accR[1][4*q4+0] = fmaf(a1a[q], wrv.x, accR[1][4*q4+0]);
        accR[1][4*q4+1] = fmaf(a1a[q], wrv.y, accR[1][4*q4+1]);
        accR[1][4*q4+2] = fmaf(a1a[q], wrv.z, accR[1][4*q4+2]);
        accR[1][4*q4+3] = fmaf(a1a[q], wrv.w, accR[1][4*q4+3]);
      }
    }
  }
#pragma unroll
  for (int rr = 0; rr < 2; ++rr) {
    size_t ob = (((size_t)(r0 + 256 * rr)) << 6) + j0;
#pragma unroll
    for (int q4 = 0; q4 < 4; ++q4) {
      *(float4*)(XL + ob + 4 * q4) = make_float4(accL[rr][4*q4], accL[rr][4*q4+1], accL[rr][4*q4+2], accL[rr][4*q4+3]);
      *(float4*)(XR + ob + 4 * q4) = make_float4(accR[rr][4*q4], accR[rr][4*q4+1], accR[rr][4*q4+2], accR[rr][4*q4+3]);
    }
  }
}

// ---------------------------------------------------------------------------
// GATv2: wave per (g,d), lane = h. DPP reduce, 8-wide masked chunks.
// ---------------------------------------------------------------------------
__global__ __launch_bounds__(256) void k_gat(
    const float* __restrict__ XL, float* __restrict__ XR_HG,
    const float* __restrict__ EPc, const int* __restrict__ offs,
    const int* __restrict__ srcA,
    const float* __restrict__ att, const float* __restrict__ gbl) {
  int gw = (blockIdx.x * 256 + threadIdx.x) >> 6;
  int lane = threadIdx.x & 63;
  int g = gw >> 11;
  int d = gw & (Nn - 1);
  float attv = att[lane];
  float gbv = gbl[lane];
  size_t rowbase = ((size_t)gw) << 6;
  float xr = XR_HG[rowbase + lane];
  int p0 = offs[d], p1 = offs[d + 1];
  int nE = p1 - p0;
  int nE4 = nE < 64 ? nE : 64;
  int soff = 0;
  if (lane < nE4) soff = srcA[p0 + lane] << 8;           // byte offset of src row
  const char* XLg = (const char*)(XL + (((size_t)g * Nn) << 6)) + (lane << 2);
  const char* EPp = (const char*)(EPc + (((size_t)p0) << 6)) + (lane << 2);
  float Ssum = 0.f, acc = 0.f;
  int nCh = (nE4 + 7) >> 3;
  for (int c = 0; c < nCh; ++c) {
    int p = c << 3;
    float xl[8], vv[8];
#pragma unroll
    for (int u = 0; u < 8; ++u) {
      int pu = p + u;
      int pc = pu < nE4 ? pu : nE4 - 1;                  // clamp (masked later)
      int so = __shfl(soff, pc, 64);
      xl[u] = *(const float*)(XLg + so);
      float ep = *(const float*)(EPp + (pc << 8));
      float m = xl[u] + xr + ep;
      m = fmaxf(m, 0.2f * m);                            // leaky_relu(0.2)
      vv[u] = m * attv;
    }
#pragma unroll
    for (int u = 0; u < 8; ++u) vv[u] = rsum64(vv[u]);
#pragma unroll
    for (int u = 0; u < 8; ++u) {
      float v = (p + u < nE4) ? vv[u] : -1e30f;
      float w = __expf(v);
      Ssum += w;
      acc = fmaf(w, xl[u], acc);
    }
  }
  for (int p = 64; p < nE; ++p) {                        // pathological tail
    int s = srcA[p0 + p];
    float xlv = *(const float*)(XLg + (s << 8));
    float ep = *(const float*)(EPp + (p << 8));
    float m = xlv + xr + ep; m = fmaxf(m, 0.2f * m);
    float w = __expf(rsum64(m * attv));
    Ssum += w; acc = fmaf(w, xlv, acc);
  }
  XR_HG[rowbase + lane] = acc / Ssum + gbv;
}

// ---------------------------------------------------------------------------
// Per-t fused GRU step: gi = hg@WihT+bih, gh = hp@WhhT+bhh, gates, h out.
// Thread = 1 row x 16-col h-slice (all 6 gate slices). W slices (6x16 cols,
// 64 k) staged in LDS once; inner loop reads W uniform (broadcast).
// grid (Mm/256, 4).
// ---------------------------------------------------------------------------
template <int HASP>
__global__ __launch_bounds__(256) void k_gru_t(
    const float* __restrict__ hg, const float* __restrict__ hp,
    const float* __restrict__ WTl,   // [64][384] k-major: 0..191 ih, 192..383 hh
    const float* __restrict__ bih, const float* __restrict__ bhh,
    float* __restrict__ hout) {
  __shared__ float w[64 * 96];       // [k][gg*16+jj], gg: 0..2 ih(r,z,n), 3..5 hh
  int tid = threadIdx.x;
  int j0 = blockIdx.y << 4;
  for (int idx = tid; idx < 64 * 96; idx += 256) {
    int k = idx / 96, rem = idx % 96;
    int gg = rem >> 4, jj = rem & 15;
    int col = ((gg < 3) ? (gg << 6) : (192 + ((gg - 3) << 6))) + j0 + jj;
    w[idx] = WTl[k * 384 + col];
  }
  __syncthreads();
  int r = blockIdx.x * 256 + tid;
  float acc[6][16];
#pragma unroll
  for (int gg = 0; gg < 3; ++gg)
#pragma unroll
    for (int jj = 0; jj < 16; ++jj) {
      acc[gg][jj]     = bih[(gg << 6) + j0 + jj];
      acc[3 + gg][jj] = bhh[(gg << 6) + j0 + jj];
    }
  const float* hgr = hg + ((size_t)r << 6);
  const float* hpr = HASP ? (hp + ((size_t)r << 6)) : nullptr;
  for (int kc = 0; kc < 16; ++kc) {
    float4 g4 = *(const float4*)(hgr + 4 * kc);
    float ga[4] = {g4.x, g4.y, g4.z, g4.w};
    float pa[4];
    if (HASP) {
      float4 p4 = *(const float4*)(hpr + 4 * kc);
      pa[0] = p4.x; pa[1] = p4.y; pa[2] = p4.z; pa[3] = p4.w;
    }
#pragma unroll
    for (int q = 0; q < 4; ++q) {
      const float4* wk = (const float4*)(w + (4 * kc + q) * 96);
#pragma unroll
      for (int gg = 0; gg < 3; ++gg)
#pragma unroll
        for (int q4 = 0; q4 < 4; ++q4) {
          float4 wv = wk[(gg << 2) + q4];
          acc[gg][4*q4+0] = fmaf(ga[q], wv.x, acc[gg][4*q4+0]);
          acc[gg][4*q4+1] = fmaf(ga[q], wv.y, acc[gg][4*q4+1]);
          acc[gg][4*q4+2] = fmaf(ga[q], wv.z, acc[gg][4*q4+2]);
          acc[gg][4*q4+3] = fmaf(ga[q], wv.w, acc[gg][4*q4+3]);
        }
      if (HASP) {
#pragma unroll
        for (int gg = 0; gg < 3; ++gg)
#pragma unroll
          for (int q4 = 0; q4 < 4; ++q4) {
            float4 wv = wk[12 + (gg << 2) + q4];
            acc[3+gg][4*q4+0] = fmaf(pa[q], wv.x, acc[3+gg][4*q4+0]);
            acc[3+gg][4*q4+1] = fmaf(pa[q], wv.y, acc[3+gg][4*q4+1]);
            acc[3+gg][4*q4+2] = fmaf(pa[q], wv.z, acc[3+gg][4*q4+2]);
            acc[3+gg][4*q4+3] = fmaf(pa[q], wv.w, acc[3+gg][4*q4+3]);
          }
      }
    }
  }
  float hv[16];
#pragma unroll
  for (int jj = 0; jj < 16; ++jj) hv[jj] = 0.f;
  if (HASP) {
#pragma unroll
    for (int q4 = 0; q4 < 4; ++q4) {
      float4 t = *(const float4*)(hpr + j0 + 4 * q4);
      hv[4*q4] = t.x; hv[4*q4+1] = t.y; hv[4*q4+2] = t.z; hv[4*q4+3] = t.w;
    }
  }
  float* op = hout + ((size_t)r << 6) + j0;
#pragma unroll
  for (int q4 = 0; q4 < 4; ++q4) {
    float o[4];
#pragma unroll
    for (int u = 0; u < 4; ++u) {
      int jj = 4 * q4 + u;
      float rg = sigf(acc[0][jj] + acc[3][jj]);
      float zg = sigf(acc[1][jj] + acc[4][jj]);
      float ng = tanhfast(acc[2][jj] + rg * acc[5][jj]);
      o[u] = (1.f - zg) * ng + zg * hv[jj];
    }
    *(float4*)(op + 4 * q4) = make_float4(o[0], o[1], o[2], o[3]);
  }
}

// ---------------------------------------------------------------------------
// Output heads
// ---------------------------------------------------------------------------
__global__ __launch_bounds__(256) void k_heads(
    const float* __restrict__ Xb,
    const float* __restrict__ oW1, const float* __restrict__ ob1,
    const float* __restrict__ oW2, const float* __restrict__ ob2,
    const float* __restrict__ dW1, const float* __restrict__ db1,
    const float* __restrict__ dW2, const float* __restrict__ db2,
    float* __restrict__ out) {
  __shared__ float w1o[Hh * HB2], w1d[Hh * HB2];
  __shared__ float w2o[HB2], w2d[HB2], b1o[HB2], b1d[HB2];
  int tid = threadIdx.x;
  for (int idx = tid; idx < Hh * HB2; idx += 256) { w1o[idx] = oW1[idx]; w1d[idx] = dW1[idx]; }
  if (tid < HB2) { w2o[tid] = oW2[tid]; w2d[tid] = dW2[tid]; b1o[tid] = ob1[tid]; b1d[tid] = db1[tid]; }
  __syncthreads();
  int r = blockIdx.x * 256 + tid;
  int b = r >> 11, n = r & (Nn - 1);
  const float* xrow = Xb + (((size_t)b * Ss + (Ss - 1)) * Nn + n) * Hh;
  float x[Hh];
  const float4* xp = (const float4*)xrow;
#pragma unroll
  for (int q = 0; q < Hh / 4; ++q) {
    float4 v = xp[q];
    x[4*q] = v.x; x[4*q+1] = v.y; x[4*q+2] = v.z; x[4*q+3] = v.w;
  }
  float acco = ob2[0], accd = db2[0];
  for (int j = 0; j < HB2; ++j) {
    float ho = b1o[j], hd = b1d[j];
#pragma unroll
    for (int k = 0; k < Hh; ++k) {
      ho += x[k] * w1o[k * HB2 + j];
      hd += x[k] * w1d[k * HB2 + j];
    }
    acco += fmaxf(ho, 0.f) * w2o[j];
    accd += fmaxf(hd, 0.f) * w2d[j];
  }
  out[r] = acco;
  out[Bb * Nn + r] = accd;
}

// ---------------------------------------------------------------------------
extern "C" void kernel_launch(void* const* d_in, const int* in_sizes, int n_in,
                              void* d_out, int out_size, void* d_ws, size_t ws_size,
                              hipStream_t stream) {
  const float* x   = (const float*)d_in[0];
  const int*   ei  = (const int*)d_in[1];
  const float* ea  = (const float*)d_in[2];
  const float* Wp  = (const float*)d_in[3];
  const float* bp  = (const float*)d_in[4];
  const float* Wl  = (const float*)d_in[5];
  const float* bl  = (const float*)d_in[6];
  const float* Wr  = (const float*)d_in[7];
  const float* br  = (const float*)d_in[8];
  const float* We  = (const float*)d_in[9];
  const float* att = (const float*)d_in[10];
  const float* gb  = (const float*)d_in[11];
  const float* Wih = (const float*)d_in[12];
  const float* Whh = (const float*)d_in[13];
  const float* bih = (const float*)d_in[14];
  const float* bhh = (const float*)d_in[15];
  const float* oW1 = (const float*)d_in[16];
  const float* ob1 = (const float*)d_in[17];
  const float* oW2 = (const float*)d_in[18];
  const float* ob2 = (const float*)d_in[19];
  const float* dW1 = (const float*)d_in[20];
  const float* db1 = (const float*)d_in[21];
  const float* dW2 = (const float*)d_in[22];
  const float* db2 = (const float*)d_in[23];
  float* out = (float*)d_out;

  // workspace layout (floats)
  float* f    = (float*)d_ws;
  float* Xb   = f;                          // 131072*64
  float* XLb  = Xb  + (size_t)RTOT * Hh;    // 131072*64
  float* XRb  = XLb + (size_t)RTOT * Hh;    // 131072*64 (hg after k_gat)
  float* EPc  = XRb + (size_t)RTOT * Hh;    // 18432*64 (CSR order)
  float* WTb  = EPc + (size_t)E2c * Hh;     // 2*64*384
  float* cntF = WTb + 2 * 64 * 384;         // 2048
  float* loopA = cntF + Nn;                 // 2048*8
  int*   fillI = (int*)(loopA + Nn * EFf);  // 2048
  int*   offs  = fillI + Nn;                // 2049 (+pad)
  int*   posOf = offs + 2052;               // 18432
  int*   srcA  = posOf + E2c;               // 18432

  hipMemsetAsync(cntF, 0, (size_t)(Nn + Nn * EFf + Nn) * 4, stream);

  k_loop_accum<<<dim3(Ee * EFf / 256), 256, 0, stream>>>(ei, ea, cntF, loopA);
  k_loop_div<<<dim3(Nn * EFf / 256), 256, 0, stream>>>(loopA, cntF);
  k_scan<<<1, 256, 0, stream>>>(cntF, offs);
  k_scatter<<<dim3((E2c + 255) / 256), 256, 0, stream>>>(ei, offs, fillI, posOf, srcA);
  k_wtr<<<dim3(2 * 64 * 384 / 256), 256, 0, stream>>>(Wih, Whh, WTb);

  // X = x @ Wp + bp
  k_proj<<<dim3(RTOT / 512, 4), 256, 0, stream>>>(x, Wp, bp, Xb);

  for (int l = 0; l < 2; ++l) {
    k_ep<<<dim3(E2c * Hh / 256), 256, 0, stream>>>(
        ea, loopA, We + (size_t)l * EFf * Hh, posOf, EPc);
    k_xlr<<<dim3(RTOT / 512, 4), 256, 0, stream>>>(
        Xb, Wl + (size_t)l * Hh * Hh, bl + (size_t)l * Hh,
        Wr + (size_t)l * Hh * Hh, br + (size_t)l * Hh, XLb, XRb);
    k_gat<<<dim3(RTOT * Hh / 256), 256, 0, stream>>>(
        XLb, XRb, EPc, offs, srcA, att + (size_t)l * Hh, gb + (size_t)l * Hh);
    const float* WTl = WTb + (size_t)l * 64 * 384;
    const float* bih_l = bih + (size_t)l * 192;
    const float* bhh_l = bhh + (size_t)l * 192;
    for (int t = 0; t < Bb; ++t) {
      const float* hg_t = XRb + (size_t)t * Mm * Hh;
      float* h_out = Xb + (size_t)t * Mm * Hh;
      if (t == 0) {
        k_gru_t<0><<<dim3(Mm / 256, 4), 256, 0, stream>>>(
            hg_t, nullptr, WTl, bih_l, bhh_l, h_out);
      } else {
        const float* h_prev = Xb + (size_t)(t - 1) * Mm * Hh;
        k_gru_t<1><<<dim3(Mm / 256, 4), 256, 0, stream>>>(
            hg_t, h_prev, WTl, bih_l, bhh_l, h_out);
      }
    }
  }

  k_heads<<<dim3(Bb * Nn / 256), 256, 0, stream>>>(
      Xb, oW1, ob1, oW2, ob2, dW1, db1, dW2, db2, out);
}